// Round 1
// baseline (304.863 us; speedup 1.0000x reference)
//
#include <hip/hip_runtime.h>
#include <math.h>

#define Nn 6144
#define Cc 128
#define NHD 2
#define MAXDEG 1024

// ---------------- warp/block reduction helpers ----------------
__device__ __forceinline__ float wave_red_sum(float v) {
#pragma unroll
  for (int o = 32; o; o >>= 1) v += __shfl_xor(v, o);
  return v;
}

// reduce (a,b) across a 256-thread block. red = float[8] LDS scratch.
template <bool IS_MAX>
__device__ __forceinline__ void block_red2(float& a, float& b, float* red) {
#pragma unroll
  for (int o = 32; o; o >>= 1) {
    float ta = __shfl_xor(a, o), tb = __shfl_xor(b, o);
    if (IS_MAX) { a = fmaxf(a, ta); b = fmaxf(b, tb); }
    else        { a += ta;          b += tb;          }
  }
  int wid = threadIdx.x >> 6;
  __syncthreads();  // protect red from previous use
  if ((threadIdx.x & 63) == 0) { red[wid] = a; red[4 + wid] = b; }
  __syncthreads();
  if (IS_MAX) {
    a = fmaxf(fmaxf(red[0], red[1]), fmaxf(red[2], red[3]));
    b = fmaxf(fmaxf(red[4], red[5]), fmaxf(red[6], red[7]));
  } else {
    a = red[0] + red[1] + red[2] + red[3];
    b = red[4] + red[5] + red[6] + red[7];
  }
}

// ---------------- kernel 1: x_norm = LN(x; g1,b1) ----------------
__global__ __launch_bounds__(256) void k_ln(const float* __restrict__ x,
                                            const float* __restrict__ g,
                                            const float* __restrict__ b,
                                            float* __restrict__ xn) {
  int wid = threadIdx.x >> 6, lane = threadIdx.x & 63;
  int row = blockIdx.x * 4 + wid;
  float2 v = ((const float2*)(x + (size_t)row * Cc))[lane];
  float s = v.x + v.y;
#pragma unroll
  for (int o = 32; o; o >>= 1) s += __shfl_xor(s, o);
  float mean = s * (1.0f / Cc);
  float dx = v.x - mean, dy = v.y - mean;
  float q = dx * dx + dy * dy;
#pragma unroll
  for (int o = 32; o; o >>= 1) q += __shfl_xor(q, o);
  float rstd = rsqrtf(q * (1.0f / Cc) + 1e-5f);
  int c = lane * 2;
  float* o = xn + (size_t)row * Cc;
  o[c]     = dx * rstd * g[c] + b[c];
  o[c + 1] = dy * rstd * g[c + 1] + b[c + 1];
}

// ---------------- tiled fp32 GEMM: out[head][r][c] = sum_k A[r][k]*B[head][c][k]
// MODE 0: plain store (h = x_norm @ ff0^T), A shared across heads
// MODE 1: elu(v)*0.5 store (per-head FF1 output), A has per-head offset
template <int MODE>
__global__ __launch_bounds__(256) void k_gemm(const float* __restrict__ A,
                                              const float* __restrict__ Bw,
                                              float* __restrict__ out) {
  __shared__ float As[64][68];   // [k][r], padded (2-way conflict max: free)
  __shared__ float Bs[64][132];  // [k][c], padded
  const int t = threadIdx.x;
  const int head = blockIdx.y;
  const int row0 = blockIdx.x * 64;
  const float* Ah = A + (MODE == 1 ? (size_t)head * Nn * Cc : (size_t)0);
  const float* Bh = Bw + (size_t)head * Cc * Cc;
  const int tr = t & 15, tc = t >> 4;
  const int r0 = tr * 4, c0 = tc * 8;
  float acc[4][8];
#pragma unroll
  for (int i = 0; i < 4; i++)
#pragma unroll
    for (int j = 0; j < 8; j++) acc[i][j] = 0.f;

  for (int kt = 0; kt < Cc; kt += 64) {
    __syncthreads();
    // stage A tile transposed: As[k][r]
    for (int i = t; i < 1024; i += 256) {
      int rr = i >> 4, k4 = i & 15;
      float4 v = *(const float4*)(Ah + (size_t)(row0 + rr) * Cc + kt + k4 * 4);
      As[k4 * 4 + 0][rr] = v.x; As[k4 * 4 + 1][rr] = v.y;
      As[k4 * 4 + 2][rr] = v.z; As[k4 * 4 + 3][rr] = v.w;
    }
    // stage B tile transposed: Bs[k][c]
    for (int i = t; i < 2048; i += 256) {
      int cc2 = i >> 4, k4 = i & 15;
      float4 v = *(const float4*)(Bh + (size_t)cc2 * Cc + kt + k4 * 4);
      Bs[k4 * 4 + 0][cc2] = v.x; Bs[k4 * 4 + 1][cc2] = v.y;
      Bs[k4 * 4 + 2][cc2] = v.z; Bs[k4 * 4 + 3][cc2] = v.w;
    }
    __syncthreads();
#pragma unroll
    for (int k = 0; k < 64; k++) {
      float4 a  = *(const float4*)&As[k][r0];
      float4 b0 = *(const float4*)&Bs[k][c0];
      float4 b1 = *(const float4*)&Bs[k][c0 + 4];
      float av[4] = {a.x, a.y, a.z, a.w};
      float bv[8] = {b0.x, b0.y, b0.z, b0.w, b1.x, b1.y, b1.z, b1.w};
#pragma unroll
      for (int i = 0; i < 4; i++)
#pragma unroll
        for (int j = 0; j < 8; j++) acc[i][j] = fmaf(av[i], bv[j], acc[i][j]);
    }
  }
#pragma unroll
  for (int i = 0; i < 4; i++) {
    float o[8];
#pragma unroll
    for (int j = 0; j < 8; j++) {
      float v = acc[i][j];
      if (MODE == 1) { v = (v > 0.f) ? v : (expf(v) - 1.f); v *= 0.5f; }
      o[j] = v;
    }
    float* op = out + ((size_t)head * Nn + row0 + r0 + i) * Cc + c0;
    *(float4*)(op)     = make_float4(o[0], o[1], o[2], o[3]);
    *(float4*)(op + 4) = make_float4(o[4], o[5], o[6], o[7]);
  }
}

// ---------------- kernel 2b: s_src/s_dst = h . attn_w halves ----------------
__global__ __launch_bounds__(256) void k_attn_s(const float* __restrict__ h,
                                                const float* __restrict__ aw,
                                                float* __restrict__ ssrc,
                                                float* __restrict__ sdst) {
  int wid = threadIdx.x >> 6, lane = threadIdx.x & 63;
  int row = blockIdx.x * 4 + wid;
#pragma unroll
  for (int hd = 0; hd < NHD; hd++) {
    float2 v  = ((const float2*)(h + ((size_t)hd * Nn + row) * Cc))[lane];
    float2 w1 = ((const float2*)(aw + hd * 2 * Cc))[lane];
    float2 w2 = ((const float2*)(aw + hd * 2 * Cc + Cc))[lane];
    float a = v.x * w1.x + v.y * w1.y;
    float b = v.x * w2.x + v.y * w2.y;
#pragma unroll
    for (int o = 32; o; o >>= 1) { a += __shfl_xor(a, o); b += __shfl_xor(b, o); }
    if (lane == 0) { ssrc[hd * Nn + row] = a; sdst[hd * Nn + row] = b; }
  }
}

// ---------------- kernel 3: per-row fused attention + residual + LN2 --------
// one block per row; both heads. Softmax support == mask (NEG underflows to 0).
__global__ __launch_bounds__(256) void k_attn(
    const float* __restrict__ adj, const float* __restrict__ x,
    const float* __restrict__ h, const float* __restrict__ ssrc,
    const float* __restrict__ sdst, const float* __restrict__ g2,
    const float* __restrict__ b2, float* __restrict__ att_out) {
  __shared__ int nbr[MAXDEG];
  __shared__ float wts[NHD][MAXDEG];
  __shared__ float red[8];
  __shared__ int cnt;
  const int t = threadIdx.x;
  const int r = blockIdx.x;
  if (t == 0) cnt = 0;
  __syncthreads();
  // phase A: scan adjacency row -> compact neighbor list (plus self-loop)
  const float4* arow = (const float4*)(adj + (size_t)r * Nn);
  for (int i = t; i < Nn / 4; i += 256) {
    float4 v = arow[i];
    int j = i * 4;
    if (v.x > 0.f || j + 0 == r) { int p = atomicAdd(&cnt, 1); if (p < MAXDEG) nbr[p] = j + 0; }
    if (v.y > 0.f || j + 1 == r) { int p = atomicAdd(&cnt, 1); if (p < MAXDEG) nbr[p] = j + 1; }
    if (v.z > 0.f || j + 2 == r) { int p = atomicAdd(&cnt, 1); if (p < MAXDEG) nbr[p] = j + 2; }
    if (v.w > 0.f || j + 3 == r) { int p = atomicAdd(&cnt, 1); if (p < MAXDEG) nbr[p] = j + 3; }
  }
  __syncthreads();
  const int deg = min(cnt, MAXDEG);
  const float s0 = ssrc[r], s1 = ssrc[Nn + r];
  // phase B1: logits + max
  float m0 = -3.0e38f, m1 = -3.0e38f;
  for (int k = t; k < deg; k += 256) {
    int j = nbr[k];
    float e0 = s0 + sdst[j];
    float e1 = s1 + sdst[Nn + j];
    e0 = (e0 > 0.f) ? e0 : 0.01f * e0;  // leaky_relu slope 0.01
    e1 = (e1 > 0.f) ? e1 : 0.01f * e1;
    wts[0][k] = e0; wts[1][k] = e1;
    m0 = fmaxf(m0, e0); m1 = fmaxf(m1, e1);
  }
  block_red2<true>(m0, m1, red);
  // phase B2: exp + sum
  float l0 = 0.f, l1 = 0.f;
  for (int k = t; k < deg; k += 256) {
    float w0 = __expf(wts[0][k] - m0); wts[0][k] = w0; l0 += w0;
    float w1 = __expf(wts[1][k] - m1); wts[1][k] = w1; l1 += w1;
  }
  block_red2<false>(l0, l1, red);
  // phase C: att[c] = (1/l) * sum_k w_k * h[head][nbr_k][c] + x[r][c]
  const int hd = t >> 7;
  const int c = t & 127;
  const float inv = 1.0f / (hd ? l1 : l0);
  const float* hp = h + (size_t)hd * Nn * Cc + c;
  const float* wrow = wts[hd];
  float acc = 0.f;
#pragma unroll 4
  for (int k = 0; k < deg; k++) acc += wrow[k] * hp[(size_t)nbr[k] * Cc];
  float att = fmaf(acc, inv, x[(size_t)r * Cc + c]);
  // phase D: LN over the 128 channels of this head (2 waves per head)
  float s = wave_red_sum(att);
  int wid = t >> 6;
  __syncthreads();
  if ((t & 63) == 0) red[wid] = s;
  __syncthreads();
  float mean = (red[hd * 2] + red[hd * 2 + 1]) * (1.0f / Cc);
  float d = att - mean;
  float q = wave_red_sum(d * d);
  __syncthreads();
  if ((t & 63) == 0) red[wid] = q;
  __syncthreads();
  float var = (red[hd * 2] + red[hd * 2 + 1]) * (1.0f / Cc);
  float rstd = rsqrtf(var + 1e-5f);
  att_out[((size_t)hd * Nn + r) * Cc + c] = d * rstd * g2[c] + b2[c];
}

// ---------------- kernel 5: out = outh[0] + outh[1] ----------------
__global__ __launch_bounds__(256) void k_combine(const float* __restrict__ a,
                                                 const float* __restrict__ b,
                                                 float* __restrict__ o) {
  int i = (blockIdx.x * 256 + threadIdx.x) * 4;
  float4 va = *(const float4*)(a + i);
  float4 vb = *(const float4*)(b + i);
  *(float4*)(o + i) = make_float4(va.x + vb.x, va.y + vb.y, va.z + vb.z, va.w + vb.w);
}

extern "C" void kernel_launch(void* const* d_in, const int* in_sizes, int n_in,
                              void* d_out, int out_size, void* d_ws, size_t ws_size,
                              hipStream_t stream) {
  const float* x   = (const float*)d_in[0];
  const float* adj = (const float*)d_in[1];
  const float* ff0 = (const float*)d_in[2];
  const float* ff1 = (const float*)d_in[3];
  const float* aw  = (const float*)d_in[4];
  const float* g1  = (const float*)d_in[5];
  const float* b1  = (const float*)d_in[6];
  const float* g2  = (const float*)d_in[7];
  const float* b2  = (const float*)d_in[8];
  float* out = (float*)d_out;

  float* ws    = (float*)d_ws;
  float* xnorm = ws;                                  // Nn*Cc
  float* h     = xnorm + (size_t)Nn * Cc;             // 2*Nn*Cc
  float* ssrc  = h + (size_t)2 * Nn * Cc;             // 2*Nn
  float* sdst  = ssrc + 2 * Nn;                       // 2*Nn
  float* attn  = sdst + 2 * Nn;                       // 2*Nn*Cc
  float* outh  = attn + (size_t)2 * Nn * Cc;          // 2*Nn*Cc
  // total ws use: ~22.1 MB (fp32)

  hipLaunchKernelGGL(k_ln, dim3(Nn / 4), dim3(256), 0, stream, x, g1, b1, xnorm);
  hipLaunchKernelGGL((k_gemm<0>), dim3(Nn / 64, 2), dim3(256), 0, stream, xnorm, ff0, h);
  hipLaunchKernelGGL(k_attn_s, dim3(Nn / 4), dim3(256), 0, stream, h, aw, ssrc, sdst);
  hipLaunchKernelGGL(k_attn, dim3(Nn), dim3(256), 0, stream, adj, x, h, ssrc, sdst, g2, b2, attn);
  hipLaunchKernelGGL((k_gemm<1>), dim3(Nn / 64, 2), dim3(256), 0, stream, attn, ff1, outh);
  hipLaunchKernelGGL(k_combine, dim3((Nn * Cc) / 1024), dim3(256), 0, stream,
                     outh, outh + (size_t)Nn * Cc, out);
}